// Round 8
// baseline (24609.114 us; speedup 1.0000x reference)
//
#include <hip/hip_runtime.h>
#include <math.h>

#define DDIM 512
#define TLEN 128
#define VDIM 32000

typedef _Float16 f16x8 __attribute__((ext_vector_type(8)));
typedef float    f32x4 __attribute__((ext_vector_type(4)));
typedef _Float16 h2    __attribute__((ext_vector_type(2)));

// exchange buffer layout (per WG, stride 4096B in d_ws):
//   [0,2048)    : conv sp slots   uint2[2 parity][128 i]  (4 f16 per i: r0..3)
//   [2048,2176) : conv partials   float4[2 parity][4 r]   {S, S2, SX, 0}
//   [2304,2432) : LN partials     float4[2 parity][4 r]   {Sev, Sev2, Sevc, 0}
#define EX_STRIDE 4096
#define SP_OFF(p)  ((p) * 1024)
#define CPT_OFF(p) (2048 + (p) * 64)
#define LPT_OFF(p) (2304 + (p) * 64)

__device__ __forceinline__ unsigned int pkh2(float a, float b) {
  h2 v; v.x = (_Float16)a; v.y = (_Float16)b;
  return __builtin_bit_cast(unsigned int, v);
}
__device__ __forceinline__ float h2f(unsigned short h) {
  return (float)__builtin_bit_cast(_Float16, h);
}
__device__ __forceinline__ unsigned short f2h(float f) {
  return __builtin_bit_cast(unsigned short, (_Float16)f);
}

__device__ __forceinline__ float tanh_fast(float x) {
  const float e = exp2f(x * 2.885390081777927f);   // e^(2x)
  return 1.f - 2.f / (e + 1.f);
}

// ---- pack diffusion into MFMA A-fragment order (unchanged, validated) -------
// frag (it 0..31, kt 0..15), lane l, elem e: val = diff[it*16+(l&15)][kt*32+(l>>4)*8+e]
__global__ __launch_bounds__(256) void pack_diffusion(
    const float* __restrict__ A, uint4* __restrict__ pk)
{
  const int slot = blockIdx.x * 256 + threadIdx.x;   // 0..32767
  const int l  = slot & 63;
  const int fr = slot >> 6;
  const int kt = fr & 15;
  const int it = fr >> 4;
  const float* src = A + (size_t)(it * 16 + (l & 15)) * DDIM + kt * 32 + (l >> 4) * 8;
  pk[slot] = make_uint4(pkh2(src[0], src[1]), pkh2(src[2], src[3]),
                        pkh2(src[4], src[5]), pkh2(src[6], src[7]));
}

// ---- cooperative recurrence: 64 groups x 4 WGs; WG owns 128 state dims ------
__global__ __launch_bounds__(512, 2) void attractor_coop(
    const int*    __restrict__ tokens,
    const float*  __restrict__ embed,
    const uint4*  __restrict__ Apk,
    const float*  __restrict__ gamma_p,
    const float*  __restrict__ beta_p,
    float*        __restrict__ comb,      // [256][512]
    unsigned int* flagbuf,                // [256] zeroed before launch
    unsigned char* exch)                  // 256 * 4096B
{
  const int tid = threadIdx.x;
  const int w   = tid >> 6;        // wave 0..7  (owns i_local = w*16..w*16+15)
  const int l   = tid & 63;
  const int g   = l >> 4;          // 0..3
  const int n   = l & 15;          // MFMA n (col); batch row r = n&3 (x4 dup)
  const int rl  = n & 3;
  const int b     = blockIdx.x;
  const int gq    = b & 3;         // state-quarter 0..3 (i range gq*128..)
  const int grp   = b >> 2;        // batch group (rows grp*4..grp*4+3)
  const int base4 = b & ~3;
  const int row0  = grp * 4;

  __shared__ unsigned short srow[4 * 528];   // f16 state [r][i global], stride 528
  __shared__ float          sigl[4 * 136];   // sig [r][i_local], stride 136
  __shared__ float4         redcv[8][4];     // per-wave partials
  __shared__ float4         statv[4];        // conv totals per r {S, S2, SX}
  __shared__ float4         lnstv[4];        // LN totals per r {Sev, Sev2, Sevc}
  __shared__ unsigned short ownh[128 * 4];   // own sp f16 staging [i_local][r]

  unsigned char* exme = exch + (size_t)b * EX_STRIDE;

  // ---- load this wave's A-slice into registers (64 VGPRs), ONCE -----------
  const uint4* apw = Apk + (size_t)((gq * 8 + w) * 16) * 64 + l;
  const uint4 AF0  = apw[0 * 64],  AF1  = apw[1 * 64],  AF2  = apw[2 * 64];
  const uint4 AF3  = apw[3 * 64],  AF4  = apw[4 * 64],  AF5  = apw[5 * 64];
  const uint4 AF6  = apw[6 * 64],  AF7  = apw[7 * 64],  AF8  = apw[8 * 64];
  const uint4 AF9  = apw[9 * 64],  AF10 = apw[10 * 64], AF11 = apw[11 * 64];
  const uint4 AF12 = apw[12 * 64], AF13 = apw[13 * 64], AF14 = apw[14 * 64];
  const uint4 AF15 = apw[15 * 64];

  for (int x = tid; x < 4 * 528; x += 512) srow[x] = 0;
  if (tid < 4) { statv[tid] = make_float4(0.f, 0.f, 0.f, 0.f); }

  const float gamma = gamma_p[0];
  const float bss   = beta_p[0] * 0.5f;   // beta * SIGNAL_SCALE

  float fs[4] = {0.f, 0.f, 0.f, 0.f};     // normalized fast, C-layout (qq)
  float sl[4] = {0.f, 0.f, 0.f, 0.f};     // slow
  float sl2   = 0.f;                      // ||slow||^2 for lane's r

  __syncthreads();

  unsigned int e = 0;   // exchange counter (uniform across threads)

  for (int t = 0; t < TLEN; ++t) {
    //================ token section: thread = (rt = tid>>7, it = tid&127) ===
    {
      const int rt = tid >> 7;
      const int it = tid & 127;
      const int ig = gq * 128 + it;
      const int tok = tokens[(row0 + rt) * TLEN + t];
      const float ev = embed[(size_t)tok * DDIM + ig];

      const float4 st  = statv[rt];              // prev conv totals
      const float spn   = sqrtf(st.y);
      const float ispn  = 1.f / (spn + 1e-8f);
      const float fnorm = spn * ispn;            // ||fast|| (0 at t=0)
      const float invfn = 1.f / (fnorm + 1e-6f);
      const float ctx   = h2f(srow[rt * 528 + ig]) * invfn;

      float p0 = ev, p1 = ev * ev, p2 = ev * ctx;
      #pragma unroll
      for (int off = 32; off >= 1; off >>= 1) {
        p0 += __shfl_xor(p0, off);
        p1 += __shfl_xor(p1, off);
        p2 += __shfl_xor(p2, off);
      }
      if (l == 0) redcv[w][0] = make_float4(p0, p1, p2, 0.f);
      __syncthreads();
      const int p = t & 1;
      if (tid < 4) {
        const float4 a = redcv[2 * tid][0];
        const float4 bb = redcv[2 * tid + 1][0];
        *(float4*)(exme + LPT_OFF(p) + tid * 16) =
            make_float4(a.x + bb.x, a.y + bb.y, a.z + bb.z, 0.f);
      }
      // ---- exchange ----
      ++e;
      __syncthreads();                                    // drains stores (vmcnt)
      if (tid == 0)
        __hip_atomic_store(&flagbuf[b], e, __ATOMIC_RELEASE, __HIP_MEMORY_SCOPE_AGENT);
      if (tid < 3) {
        const int pb = base4 + ((gq + 1 + tid) & 3);
        while (__hip_atomic_load(&flagbuf[pb], __ATOMIC_ACQUIRE,
                                 __HIP_MEMORY_SCOPE_AGENT) < e) {
          __builtin_amdgcn_s_sleep(1);
        }
      }
      __syncthreads();
      __threadfence();
      if (tid < 4) {
        float a0 = 0.f, a1 = 0.f, a2 = 0.f;
        #pragma unroll
        for (int q2 = 0; q2 < 4; ++q2) {
          const float4 v = *(const float4*)(exch + (size_t)(base4 + q2) * EX_STRIDE
                                            + LPT_OFF(p) + tid * 16);
          a0 += v.x; a1 += v.y; a2 += v.z;
        }
        lnstv[tid] = make_float4(a0, a1, a2, 0.f);
      }
      __syncthreads();
      // LN + signal for this thread's (rt, it)
      {
        const float4 ln = lnstv[rt];
        const float mu  = ln.x * (1.f / DDIM);
        float var = ln.y * (1.f / DDIM) - mu * mu;
        var = fmaxf(var, 0.f);
        const float inv  = rsqrtf(var + 1e-5f);
        const float n2y  = (float)DDIM * var / (var + 1e-5f);
        const float invn = 1.f / fmaxf(sqrtf(n2y), 1e-12f);
        const float bi   = inv * invn;
        const float smn  = st.x * ispn;                 // sum(fast)
        const float sctx = invfn * smn;
        const float bdot = bi * (ln.z - mu * sctx);
        const float b2   = n2y * invn * invn;
        const float cn2  = fnorm * fnorm * invfn * invfn;
        const float sg2  = b2 + 2.f * gamma * bdot + gamma * gamma * cn2;
        const float isig = 1.f / (sqrtf(fmaxf(sg2, 0.f)) + 1e-6f);
        sigl[rt * 136 + it] = ((ev - mu) * bi + gamma * ctx) * isig;
      }
      __syncthreads();
    }

    //================ 4 conv steps ==========================================
    #pragma unroll 1
    for (int k = 0; k < 4; ++k) {
      const bool last = (k == 3);
      const int  p    = k & 1;

      f32x4 C = (f32x4){0.f, 0.f, 0.f, 0.f};
      #define MSTEP(AF, KT)                                                   \
        { const f16x8 bf = *(const f16x8*)&srow[rl * 528 + (KT) * 32 + g * 8];\
          C = __builtin_amdgcn_mfma_f32_16x16x32_f16(                         \
                __builtin_bit_cast(f16x8, AF), bf, C, 0, 0, 0); }
      MSTEP(AF0,  0)  MSTEP(AF1,  1)  MSTEP(AF2,  2)  MSTEP(AF3,  3)
      MSTEP(AF4,  4)  MSTEP(AF5,  5)  MSTEP(AF6,  6)  MSTEP(AF7,  7)
      MSTEP(AF8,  8)  MSTEP(AF9,  9)  MSTEP(AF10, 10) MSTEP(AF11, 11)
      MSTEP(AF12, 12) MSTEP(AF13, 13) MSTEP(AF14, 14) MSTEP(AF15, 15)
      #undef MSTEP

      // elementwise update (state in C-layout: i_local = w*16 + g*4 + qq)
      const float4 stold = statv[rl];
      const float ispo   = 1.f / (sqrtf(stold.y) + 1e-8f);
      const float meanr  = stold.x * ispo * (1.f / DDIM);
      const f32x4 sgf = *(const f32x4*)&sigl[rl * 136 + w * 16 + g * 4];
      float sp[4];
      float vs = 0.f, v2 = 0.f, vx = 0.f;
      #pragma unroll
      for (int qq = 0; qq < 4; ++qq) {
        const float s  = fs[qq];
        const float th = tanh_fast(s - meanr);
        const float dr = C[qq] + 0.008f * th + bss * sgf[qq] - 0.1f * s;
        sp[qq] = fmaf(0.04f, dr, s);           // nan_to_num/clip no-ops
        vs += sp[qq]; v2 += sp[qq] * sp[qq];
        if (last) vx += sl[qq] * sp[qq];
      }
      // sum over g (lanes xor 16,32); lanes l<4 then hold totals for r=l
      vs += __shfl_xor(vs, 16); vs += __shfl_xor(vs, 32);
      v2 += __shfl_xor(v2, 16); v2 += __shfl_xor(v2, 32);
      vx += __shfl_xor(vx, 16); vx += __shfl_xor(vx, 32);
      if (l < 4) redcv[w][l] = make_float4(vs, v2, vx, 0.f);
      if (n < 4) {   // stage own sp as f16 (dedupe: one lane per (i,r))
        #pragma unroll
        for (int qq = 0; qq < 4; ++qq)
          ownh[(w * 16 + g * 4 + qq) * 4 + n] = f2h(sp[qq]);
      }
      __syncthreads();
      // publish
      if (tid < 128)
        *(uint2*)(exme + SP_OFF(p) + tid * 8) = ((const uint2*)ownh)[tid];
      if (tid < 4) {
        float a0 = 0.f, a1 = 0.f, a2 = 0.f;
        #pragma unroll
        for (int wv = 0; wv < 8; ++wv) {
          const float4 v = redcv[wv][tid];
          a0 += v.x; a1 += v.y; a2 += v.z;
        }
        *(float4*)(exme + CPT_OFF(p) + tid * 16) = make_float4(a0, a1, a2, 0.f);
      }
      // ---- exchange ----
      ++e;
      __syncthreads();
      if (tid == 0)
        __hip_atomic_store(&flagbuf[b], e, __ATOMIC_RELEASE, __HIP_MEMORY_SCOPE_AGENT);
      if (tid < 3) {
        const int pb = base4 + ((gq + 1 + tid) & 3);
        while (__hip_atomic_load(&flagbuf[pb], __ATOMIC_ACQUIRE,
                                 __HIP_MEMORY_SCOPE_AGENT) < e) {
          __builtin_amdgcn_s_sleep(1);
        }
      }
      __syncthreads();
      __threadfence();
      if (tid < 4) {
        float a0 = 0.f, a1 = 0.f, a2 = 0.f;
        #pragma unroll
        for (int q2 = 0; q2 < 4; ++q2) {
          const float4 v = *(const float4*)(exch + (size_t)(base4 + q2) * EX_STRIDE
                                            + CPT_OFF(p) + tid * 16);
          a0 += v.x; a1 += v.y; a2 += v.z;
        }
        statv[tid] = make_float4(a0, a1, a2, 0.f);
      }
      __syncthreads();
      // normalize own registers; rebuild full srow from 4 quarters
      const float4 stn = statv[rl];
      const float spn  = sqrtf(stn.y);
      const float ispn = 1.f / (spn + 1e-8f);
      #pragma unroll
      for (int qq = 0; qq < 4; ++qq) fs[qq] = sp[qq] * ispn;

      {
        const float is0 = 1.f / (sqrtf(statv[0].y) + 1e-8f);
        const float is1 = 1.f / (sqrtf(statv[1].y) + 1e-8f);
        const float is2 = 1.f / (sqrtf(statv[2].y) + 1e-8f);
        const float is3 = 1.f / (sqrtf(statv[3].y) + 1e-8f);
        const int i = tid;                 // global state index 0..511
        const int qs = i >> 7;
        const uint2 pk = *(const uint2*)(exch + (size_t)(base4 + qs) * EX_STRIDE
                                         + SP_OFF(p) + (i & 127) * 8);
        srow[0 * 528 + i] = f2h(h2f((unsigned short)(pk.x & 0xffff)) * is0);
        srow[1 * 528 + i] = f2h(h2f((unsigned short)(pk.x >> 16))    * is1);
        srow[2 * 528 + i] = f2h(h2f((unsigned short)(pk.y & 0xffff)) * is2);
        srow[3 * 528 + i] = f2h(h2f((unsigned short)(pk.y >> 16))    * is3);
      }

      if (last) {
        const float fnorm = spn * ispn;
        const float sdf   = stn.z * ispn;                 // slow·fast
        const float sn2   = 0.9025f * sl2 + 0.095f * sdf + 0.0025f * fnorm * fnorm;
        const float sn    = sqrtf(fmaxf(sn2, 0.f));
        const float scale = (sn > 0.5f) ? 0.5f / (sn + 1e-12f) : 1.f;
        #pragma unroll
        for (int qq = 0; qq < 4; ++qq)
          sl[qq] = (0.95f * sl[qq] + 0.05f * fs[qq]) * scale;
        sl2 = sn2 * scale * scale;
        if (t == TLEN - 1 && n < 4) {
          #pragma unroll
          for (int qq = 0; qq < 4; ++qq)
            comb[(size_t)(row0 + n) * DDIM + gq * 128 + w * 16 + g * 4 + qq] =
                fs[qq] + 0.3f * sl[qq];
        }
      }
      __syncthreads();
    } // conv steps
  } // tokens
}

// ---- readout GEMM: out[b][v] = Σ_d comb[b][d]·W[v][d] -----------------------
#define KC  32
#define LDT 132

__global__ __launch_bounds__(256) void logits_gemm(
    const float* __restrict__ comb,   // [256][512]
    const float* __restrict__ W,      // [32000][512]
    float*       __restrict__ out)    // [256][32000]
{
  __shared__ float wt[KC * LDT];
  __shared__ float ct[KC * LDT];

  const int tid = threadIdx.x;
  const int v0  = blockIdx.x * 128;
  const int b0  = blockIdx.y * 128;
  const int tb  = tid >> 4;
  const int tv  = tid & 15;

  float acc[8][8];
  #pragma unroll
  for (int a = 0; a < 8; ++a)
    #pragma unroll
    for (int b = 0; b < 8; ++b) acc[a][b] = 0.f;

  for (int kk = 0; kk < DDIM; kk += KC) {
    #pragma unroll
    for (int it = 0; it < 4; ++it) {
      const int l4  = tid + it * 256;
      const int row = l4 >> 3;
      const int k4  = (l4 & 7) << 2;
      const float4 gw = *(const float4*)&W[(size_t)(v0 + row) * DDIM + kk + k4];
      const float4 gc = *(const float4*)&comb[(size_t)(b0 + row) * DDIM + kk + k4];
      wt[(k4 + 0) * LDT + row] = gw.x;
      wt[(k4 + 1) * LDT + row] = gw.y;
      wt[(k4 + 2) * LDT + row] = gw.z;
      wt[(k4 + 3) * LDT + row] = gw.w;
      ct[(k4 + 0) * LDT + row] = gc.x;
      ct[(k4 + 1) * LDT + row] = gc.y;
      ct[(k4 + 2) * LDT + row] = gc.z;
      ct[(k4 + 3) * LDT + row] = gc.w;
    }
    __syncthreads();

    for (int kx = 0; kx < KC; ++kx) {
      const float4 c0 = *(const float4*)&ct[kx * LDT + tb * 8];
      const float4 c1 = *(const float4*)&ct[kx * LDT + tb * 8 + 4];
      const float4 w0 = *(const float4*)&wt[kx * LDT + tv * 8];
      const float4 w1 = *(const float4*)&wt[kx * LDT + tv * 8 + 4];
      const float cw[8] = {c0.x, c0.y, c0.z, c0.w, c1.x, c1.y, c1.z, c1.w};
      const float wv[8] = {w0.x, w0.y, w0.z, w0.w, w1.x, w1.y, w1.z, w1.w};
      #pragma unroll
      for (int ib = 0; ib < 8; ++ib)
        #pragma unroll
        for (int iv = 0; iv < 8; ++iv)
          acc[ib][iv] = fmaf(cw[ib], wv[iv], acc[ib][iv]);
    }
    __syncthreads();
  }

  #pragma unroll
  for (int ib = 0; ib < 8; ++ib) {
    const size_t base = (size_t)(b0 + tb * 8 + ib) * VDIM + v0 + tv * 8;
    *(float4*)&out[base]     = make_float4(acc[ib][0], acc[ib][1], acc[ib][2], acc[ib][3]);
    *(float4*)&out[base + 4] = make_float4(acc[ib][4], acc[ib][5], acc[ib][6], acc[ib][7]);
  }
}

extern "C" void kernel_launch(void* const* d_in, const int* in_sizes, int n_in,
                              void* d_out, int out_size, void* d_ws, size_t ws_size,
                              hipStream_t stream) {
  const int*   tokens    = (const int*)d_in[0];
  const float* embed     = (const float*)d_in[1];
  const float* readout_w = (const float*)d_in[2];
  const float* diffusion = (const float*)d_in[3];
  const float* gamma_p   = (const float*)d_in[4];
  const float* beta_p    = (const float*)d_in[5];

  float*         comb  = (float*)d_ws;                                   // 512 KB
  uint4*         Apk   = (uint4*)((char*)d_ws + 512 * 1024);             // 512 KB
  unsigned int*  flags = (unsigned int*)((char*)d_ws + 1024 * 1024);     // 1 KB
  unsigned char* exch  = (unsigned char*)d_ws + 1024 * 1024 + 4096;      // 1 MB

  hipMemsetAsync(flags, 0, 1024, stream);
  hipLaunchKernelGGL(pack_diffusion, dim3(128), dim3(256), 0, stream,
                     diffusion, Apk);

  void* args[] = {(void*)&tokens, (void*)&embed, (void*)&Apk,
                  (void*)&gamma_p, (void*)&beta_p, (void*)&comb,
                  (void*)&flags, (void*)&exch};
  hipLaunchCooperativeKernel((void*)attractor_coop, dim3(256), dim3(512),
                             args, 0, stream);

  hipLaunchKernelGGL(logits_gemm, dim3(VDIM / 128, 256 / 128), dim3(256), 0, stream,
                     comb, readout_w, (float*)d_out);
}

// Round 9
// 6184.999 us; speedup vs baseline: 3.9788x; 3.9788x over previous
//
#include <hip/hip_runtime.h>
#include <math.h>

#define DDIM 512
#define TLEN 128
#define RB   8
#define NWG  32
#define VDIM 32000
#define NWAVE 8
#define SR   528    // f16 units per srow row (2-way-bank-safe stride)
#define FR   520    // f32 units per force/slow row

typedef _Float16 f16x8 __attribute__((ext_vector_type(8)));
typedef float    f32x4 __attribute__((ext_vector_type(4)));
typedef _Float16 h2    __attribute__((ext_vector_type(2)));

__device__ __forceinline__ unsigned int pkh2(float a, float b) {
  h2 v; v.x = (_Float16)a; v.y = (_Float16)b;
  return __builtin_bit_cast(unsigned int, v);
}
__device__ __forceinline__ float h2f(unsigned short h) {
  return (float)__builtin_bit_cast(_Float16, h);
}
__device__ __forceinline__ float tanh_fast(float x) {
  const float e = exp2f(x * 2.885390081777927f);   // e^(2x)
  return 1.f - 2.f / (e + 1.f);
}

// ---- pack diffusion into MFMA A-fragment order (validated rounds 3-8) -------
// frag (it 0..31, kt 0..15), lane l, elem e: val = diff[it*16+(l&15)][kt*32+(l>>4)*8+e]
__global__ __launch_bounds__(256) void pack_diffusion(
    const float* __restrict__ A, uint4* __restrict__ pk)
{
  const int slot = blockIdx.x * 256 + threadIdx.x;   // 0..32767
  const int l  = slot & 63;
  const int fr = slot >> 6;
  const int kt = fr & 15;
  const int it = fr >> 4;
  const float* src = A + (size_t)(it * 16 + (l & 15)) * DDIM + kt * 32 + (l >> 4) * 8;
  pk[slot] = make_uint4(pkh2(src[0], src[1]), pkh2(src[2], src[3]),
                        pkh2(src[4], src[5]), pkh2(src[6], src[7]));
}

#define PF(B_, KT_)                                                          \
  {                                                                          \
    _Pragma("unroll")                                                        \
    for (int mt = 0; mt < 4; ++mt)                                           \
      B_[mt] = apw[(size_t)(mt * 16 + (KT_)) * 64];                          \
  }
#define USE(B_, KT_)                                                         \
  {                                                                          \
    const f16x8 bf = *(const f16x8*)&srow[rp][rl * SR + (KT_) * 32 + g * 8]; \
    _Pragma("unroll")                                                        \
    for (int mt = 0; mt < 4; ++mt)                                           \
      C[mt] = __builtin_amdgcn_mfma_f32_16x16x32_f16(                        \
          __builtin_bit_cast(f16x8, B_[mt]), bf, C[mt], 0, 0, 0);            \
  }

// ---- recurrence: one WG = 8 rows; unnormalized-state publish, 1 barrier/step
__global__ __launch_bounds__(512) void attractor_recurrence(
    const int*   __restrict__ tokens,
    const float* __restrict__ embed,
    const uint4* __restrict__ Apk,
    const float* __restrict__ gamma_p,
    const float* __restrict__ beta_p,
    float*       __restrict__ comb_out)   // [256][512]
{
  const int tid   = threadIdx.x;
  const int w     = tid >> 6;
  const int l     = tid & 63;
  const int g     = l >> 4;
  const int n     = l & 15;
  const int rl    = n & 7;
  const int row0  = blockIdx.x * RB;
  const int wbase = w * 64;

  __shared__ unsigned short srow[2][RB * SR];   // raw (unnormalized) state, f16
  __shared__ float  force[RB * FR];             // bss * sig
  __shared__ float  slowl[RB * FR];
  __shared__ float4 redc[2][NWAVE][RB];
  __shared__ float4 redt[NWAVE][6];
  __shared__ float2 carry[RB];                  // {S_raw, S2_raw} of fast

  for (int x = tid; x < RB * SR; x += 512) { srow[0][x] = 0; srow[1][x] = 0; }
  for (int x = tid; x < RB * FR; x += 512) slowl[x] = 0.f;

  const float gamma = gamma_p[0];
  const float bss   = beta_p[0] * 0.5f;

  float fs[4][4];                 // RAW state, MFMA C-layout [mt][q]
  #pragma unroll
  for (int mt = 0; mt < 4; ++mt)
    #pragma unroll
    for (int q = 0; q < 4; ++q) fs[mt][q] = 0.f;
  float S_reg = 0.f, S2_reg = 0.f, SX_reg = 0.f;   // raw totals for lane's rl
  float sl2 = 0.f;                                 // ||slow||^2 for lane's rl

  // prologue: embed gather for t=0
  float evc[8];
  #pragma unroll
  for (int r = 0; r < 8; ++r) {
    const int tok = tokens[(row0 + r) * TLEN + 0];
    evc[r] = embed[(size_t)tok * DDIM + tid];
  }

  __syncthreads();

  for (int t = 0; t < TLEN; ++t) {
    //=========== alpha: gathers + raw partials + carry + slow update =========
    const int tn = (t + 1 < TLEN) ? t + 1 : t;
    float evn[8];
    #pragma unroll
    for (int r = 0; r < 8; ++r) {
      const int tok = tokens[(row0 + r) * TLEN + tn];
      evn[r] = embed[(size_t)tok * DDIM + tid];
    }
    float pr[24];
    #pragma unroll
    for (int r = 0; r < 8; ++r) {
      pr[r]      = evc[r];
      pr[8 + r]  = evc[r] * evc[r];
      pr[16 + r] = evc[r] * h2f(srow[0][r * SR + tid]);   // ev . sp_raw
    }
    #pragma unroll
    for (int off = 32; off >= 1; off >>= 1)
      #pragma unroll
      for (int q = 0; q < 24; ++q)
        pr[q] += __shfl_xor(pr[q], off);
    if (l == 0) {
      #pragma unroll
      for (int q6 = 0; q6 < 6; ++q6)
        redt[w][q6] = make_float4(pr[q6*4], pr[q6*4+1], pr[q6*4+2], pr[q6*4+3]);
    }
    if (tid < 8) carry[tid] = make_float2(S_reg, S2_reg);
    if (t > 0) {   // slow update for token t-1 (uses step-3 totals in regs)
      const float sq3   = sqrtf(S2_reg);
      const float ispn3 = 1.f / (sq3 + 1e-8f);
      const float fn3   = sq3 * ispn3;
      const float sdf   = SX_reg * ispn3;
      const float sn2   = 0.9025f * sl2 + 0.095f * sdf + 0.0025f * fn3 * fn3;
      const float sn    = sqrtf(fmaxf(sn2, 0.f));
      const float scale = (sn > 0.5f) ? 0.5f / (sn + 1e-12f) : 1.f;
      sl2 = sn2 * scale * scale;
      if (n < 8) {
        #pragma unroll
        for (int mt = 0; mt < 4; ++mt) {
          const int i0 = wbase + mt * 16 + g * 4;
          f32x4 so = *(f32x4*)&slowl[rl * FR + i0];
          #pragma unroll
          for (int q = 0; q < 4; ++q)
            so[q] = (0.95f * so[q] + 0.05f * fs[mt][q] * ispn3) * scale;
          *(f32x4*)&slowl[rl * FR + i0] = so;
        }
      }
    }
    __syncthreads();   // B1

    //=========== beta: scalars per r + force =================================
    {
      float rs[24];
      #pragma unroll
      for (int q = 0; q < 24; ++q) rs[q] = 0.f;
      #pragma unroll
      for (int wv = 0; wv < NWAVE; ++wv)
        #pragma unroll
        for (int q6 = 0; q6 < 6; ++q6) {
          const float4 v = redt[wv][q6];
          rs[q6*4] += v.x; rs[q6*4+1] += v.y; rs[q6*4+2] += v.z; rs[q6*4+3] += v.w;
        }
      #pragma unroll
      for (int r = 0; r < 8; ++r) {
        const float2 cy  = carry[r];
        const float sq   = sqrtf(cy.y);
        const float ispr = 1.f / (sq + 1e-8f);
        const float fno  = sq * ispr;
        const float invf = 1.f / (fno + 1e-6f);
        const float qr   = ispr * invf;          // ctx = qr * sp_raw
        const float mu   = rs[r] * (1.f / DDIM);
        float var = rs[8 + r] * (1.f / DDIM) - mu * mu;
        var = fmaxf(var, 0.f);
        const float inv  = rsqrtf(var + 1e-5f);
        const float n2y  = (float)DDIM * var / (var + 1e-5f);
        const float invn = 1.f / fmaxf(sqrtf(n2y), 1e-12f);
        const float bi   = inv * invn;
        const float sctx = qr * cy.x;
        const float bdot = bi * (qr * rs[16 + r] - mu * sctx);
        const float b2   = n2y * invn * invn;
        const float cn2  = qr * qr * cy.y;
        const float sg2  = b2 + 2.f * gamma * bdot + gamma * gamma * cn2;
        const float isig = 1.f / (sqrtf(fmaxf(sg2, 0.f)) + 1e-6f);
        const float ctx  = qr * h2f(srow[0][r * SR + tid]);
        force[r * FR + tid] = bss * ((evc[r] - mu) * bi + gamma * ctx) * isig;
      }
    }
    __syncthreads();   // B2

    //=========== conv steps: ONE barrier each ================================
    const uint4* apw = Apk + (size_t)(w * 64) * 64 + l;
    #pragma unroll 1
    for (int k = 0; k < 4; ++k) {
      const int  rp   = k & 1;        // srow read parity
      const int  wp   = rp ^ 1;       // srow write parity
      const bool last = (k == 3);

      f32x4 C[4];
      #pragma unroll
      for (int mt = 0; mt < 4; ++mt) C[mt] = (f32x4){0.f, 0.f, 0.f, 0.f};

      uint4 A0[4], A1[4], A2[4];
      PF(A0, 0); PF(A1, 1); PF(A2, 2);
      USE(A0,  0); PF(A0,  3);
      USE(A1,  1); PF(A1,  4);
      USE(A2,  2); PF(A2,  5);
      USE(A0,  3); PF(A0,  6);
      USE(A1,  4); PF(A1,  7);
      USE(A2,  5); PF(A2,  8);
      USE(A0,  6); PF(A0,  9);
      USE(A1,  7); PF(A1, 10);
      USE(A2,  8); PF(A2, 11);
      USE(A0,  9); PF(A0, 12);
      USE(A1, 10); PF(A1, 13);
      USE(A2, 11); PF(A2, 14);
      USE(A0, 12); PF(A0, 15);
      USE(A1, 13);
      USE(A2, 14);
      USE(A0, 15);

      // elementwise on normalized state via scalar folding (fs stays raw)
      const float ispn  = 1.f / (sqrtf(S2_reg) + 1e-8f);
      const float smean = S_reg * ispn * (1.f / DDIM);
      float vs = 0.f, v2 = 0.f, vx = 0.f;
      #pragma unroll
      for (int mt = 0; mt < 4; ++mt) {
        const int i0 = wbase + mt * 16 + g * 4;
        const f32x4 ff = *(const f32x4*)&force[rl * FR + i0];
        f32x4 slv;
        if (last) slv = *(const f32x4*)&slowl[rl * FR + i0];
        #pragma unroll
        for (int q = 0; q < 4; ++q) {
          const float s   = fs[mt][q] * ispn;
          const float th  = tanh_fast(s - smean);
          const float dr  = C[mt][q] * ispn + 0.008f * th + ff[q] - 0.1f * s;
          const float spv = fmaf(0.04f, dr, s);    // nan_to_num/clip no-ops
          fs[mt][q] = spv;                          // raw for next step
          vs += spv; v2 += spv * spv;
          if (last) vx += slv[q] * spv;
        }
      }
      vs += __shfl_xor(vs, 8);  v2 += __shfl_xor(v2, 8);  vx += __shfl_xor(vx, 8);
      vs += __shfl_xor(vs, 16); v2 += __shfl_xor(v2, 16); vx += __shfl_xor(vx, 16);
      vs += __shfl_xor(vs, 32); v2 += __shfl_xor(v2, 32); vx += __shfl_xor(vx, 32);

      if (n < 8) {                       // publish raw state as f16
        #pragma unroll
        for (int mt = 0; mt < 4; ++mt) {
          const int i0 = wbase + mt * 16 + g * 4;
          uint2 pkv;
          pkv.x = pkh2(fs[mt][0], fs[mt][1]);
          pkv.y = pkh2(fs[mt][2], fs[mt][3]);
          *(uint2*)&srow[wp][rl * SR + i0] = pkv;
        }
      }
      if (l < 8) redc[rp][w][l] = make_float4(vs, v2, vx, 0.f);
      __syncthreads();                   // the ONLY barrier of this step
      float S = 0.f, S2 = 0.f, SX = 0.f;
      #pragma unroll
      for (int wv = 0; wv < NWAVE; ++wv) {
        const float4 v = redc[rp][wv][rl];
        S += v.x; S2 += v.y; SX += v.z;
      }
      S_reg = S * 0.5f; S2_reg = S2 * 0.5f; SX_reg = SX * 0.5f;  // dup x2
    }

    #pragma unroll
    for (int r = 0; r < 8; ++r) evc[r] = evn[r];
  } // tokens

  //=========== epilogue: final slow update + comb write ======================
  {
    const float sq3   = sqrtf(S2_reg);
    const float ispn3 = 1.f / (sq3 + 1e-8f);
    const float fn3   = sq3 * ispn3;
    const float sdf   = SX_reg * ispn3;
    const float sn2   = 0.9025f * sl2 + 0.095f * sdf + 0.0025f * fn3 * fn3;
    const float sn    = sqrtf(fmaxf(sn2, 0.f));
    const float scale = (sn > 0.5f) ? 0.5f / (sn + 1e-12f) : 1.f;
    if (n < 8) {
      #pragma unroll
      for (int mt = 0; mt < 4; ++mt) {
        const int i0 = wbase + mt * 16 + g * 4;
        const f32x4 so = *(const f32x4*)&slowl[rl * FR + i0];
        float4 o;
        o.x = fs[mt][0] * ispn3 + 0.3f * ((0.95f * so[0] + 0.05f * fs[mt][0] * ispn3) * scale);
        o.y = fs[mt][1] * ispn3 + 0.3f * ((0.95f * so[1] + 0.05f * fs[mt][1] * ispn3) * scale);
        o.z = fs[mt][2] * ispn3 + 0.3f * ((0.95f * so[2] + 0.05f * fs[mt][2] * ispn3) * scale);
        o.w = fs[mt][3] * ispn3 + 0.3f * ((0.95f * so[3] + 0.05f * fs[mt][3] * ispn3) * scale);
        *(float4*)&comb_out[(size_t)(row0 + rl) * DDIM + i0] = o;
      }
    }
  }
}

// ---- readout GEMM (unchanged) -----------------------------------------------
#define KC  32
#define LDT 132

__global__ __launch_bounds__(256) void logits_gemm(
    const float* __restrict__ comb,
    const float* __restrict__ W,
    float*       __restrict__ out)
{
  __shared__ float wt[KC * LDT];
  __shared__ float ct[KC * LDT];

  const int tid = threadIdx.x;
  const int v0  = blockIdx.x * 128;
  const int b0  = blockIdx.y * 128;
  const int tb  = tid >> 4;
  const int tv  = tid & 15;

  float acc[8][8];
  #pragma unroll
  for (int a = 0; a < 8; ++a)
    #pragma unroll
    for (int b = 0; b < 8; ++b) acc[a][b] = 0.f;

  for (int kk = 0; kk < DDIM; kk += KC) {
    #pragma unroll
    for (int it = 0; it < 4; ++it) {
      const int l4  = tid + it * 256;
      const int row = l4 >> 3;
      const int k4  = (l4 & 7) << 2;
      const float4 gw = *(const float4*)&W[(size_t)(v0 + row) * DDIM + kk + k4];
      const float4 gc = *(const float4*)&comb[(size_t)(b0 + row) * DDIM + kk + k4];
      wt[(k4 + 0) * LDT + row] = gw.x;
      wt[(k4 + 1) * LDT + row] = gw.y;
      wt[(k4 + 2) * LDT + row] = gw.z;
      wt[(k4 + 3) * LDT + row] = gw.w;
      ct[(k4 + 0) * LDT + row] = gc.x;
      ct[(k4 + 1) * LDT + row] = gc.y;
      ct[(k4 + 2) * LDT + row] = gc.z;
      ct[(k4 + 3) * LDT + row] = gc.w;
    }
    __syncthreads();

    for (int kx = 0; kx < KC; ++kx) {
      const float4 c0 = *(const float4*)&ct[kx * LDT + tb * 8];
      const float4 c1 = *(const float4*)&ct[kx * LDT + tb * 8 + 4];
      const float4 w0 = *(const float4*)&wt[kx * LDT + tv * 8];
      const float4 w1 = *(const float4*)&wt[kx * LDT + tv * 8 + 4];
      const float cw[8] = {c0.x, c0.y, c0.z, c0.w, c1.x, c1.y, c1.z, c1.w};
      const float wv[8] = {w0.x, w0.y, w0.z, w0.w, w1.x, w1.y, w1.z, w1.w};
      #pragma unroll
      for (int ib = 0; ib < 8; ++ib)
        #pragma unroll
        for (int iv = 0; iv < 8; ++iv)
          acc[ib][iv] = fmaf(cw[ib], wv[iv], acc[ib][iv]);
    }
    __syncthreads();
  }

  #pragma unroll
  for (int ib = 0; ib < 8; ++ib) {
    const size_t base = (size_t)(b0 + tb * 8 + ib) * VDIM + v0 + tv * 8;
    *(float4*)&out[base]     = make_float4(acc[ib][0], acc[ib][1], acc[ib][2], acc[ib][3]);
    *(float4*)&out[base + 4] = make_float4(acc[ib][4], acc[ib][5], acc[ib][6], acc[ib][7]);
  }
}

extern "C" void kernel_launch(void* const* d_in, const int* in_sizes, int n_in,
                              void* d_out, int out_size, void* d_ws, size_t ws_size,
                              hipStream_t stream) {
  const int*   tokens    = (const int*)d_in[0];
  const float* embed     = (const float*)d_in[1];
  const float* readout_w = (const float*)d_in[2];
  const float* diffusion = (const float*)d_in[3];
  const float* gamma_p   = (const float*)d_in[4];
  const float* beta_p    = (const float*)d_in[5];

  float* comb = (float*)d_ws;                              // 512 KB
  uint4* Apk  = (uint4*)((char*)d_ws + 512 * 1024);        // 512 KB

  hipLaunchKernelGGL(pack_diffusion, dim3(128), dim3(256), 0, stream,
                     diffusion, Apk);
  hipLaunchKernelGGL(attractor_recurrence, dim3(NWG), dim3(512), 0, stream,
                     tokens, embed, Apk, gamma_p, beta_p, comb);
  hipLaunchKernelGGL(logits_gemm, dim3(VDIM / 128, 256 / 128), dim3(256), 0, stream,
                     comb, readout_w, (float*)d_out);
}